// Round 1
// 76.989 us; speedup vs baseline: 1.0400x; 1.0400x over previous
//
#include <hip/hip_runtime.h>

#define NQ 10
#define NP 81
#define TT 8

// ---- per-wave LDS word offsets (1 wave = 1 batch element, 4 waves/block) ----
#define PXO   0      // px[8][81]: x_t@Wx + b, precomputed (no h dep)
#define SOFF  648    // sin of the 64 per-timestep angles (1 per lane)
#define COFF  712    // cos
#define FTO   776    // features: 5 circuits x 36 (stride 36 => 16B aligned, banks spread)
#define GOFF  956    // 50 gate pre-activations
#define HOFF  1008   // h[10] (+pad)
#define XOFF  1020   // x[8][10] staged
#define WWORDS 1100  // 4400 B per wave

__device__ __forceinline__ float sigm(float z) {
    z = fminf(fmaxf(z, -30.f), 30.f);
    return 1.f / (1.f + __expf(-z));
}
__device__ __forceinline__ float tanh_(float z) {
    z = fminf(fmaxf(z, -15.f), 15.f);
    float e = __expf(2.f * z);
    return (e - 1.f) / (e + 1.f);
}

// One wave handles one batch element through the whole T=8 scan.
// ZERO __syncthreads: all producer/consumer pairs are within a single wave
// (per-wave DS ops execute in order; wave_barrier() pins compiler ordering, free).
__global__ __launch_bounds__(256) void qlstm_kernel(
    const float* __restrict__ x, const float* __restrict__ Wx,
    const float* __restrict__ Wh, const float* __restrict__ bias,
    const float* __restrict__ R, float* __restrict__ out) {

    __shared__ __align__(16) float lds_all[4 * WWORDS];
    const int tid = threadIdx.x;
    const int wv = tid >> 6, ln = tid & 63;
    float* lds = &lds_all[wv * WWORDS];
    const int g = blockIdx.x * 4 + wv;   // batch element

    // ---- stage x for this batch (coalesced 64+16 loads)
    const float* xg = x + (size_t)g * 80;
    lds[XOFF + ln] = xg[ln];
    if (ln < 16) lds[XOFF + 64 + ln] = xg[64 + ln];

    // ---- P1 weights: lane -> columns j1=ln (0..63), j2=64+ln (ln<17 -> 64..80)
    const int j1 = ln, j2 = 64 + ln;
    const bool has2 = (ln < 17);
    float wx1[NQ], wh1[NQ], wx2[NQ], wh2[NQ];
    float b1 = bias[j1], b2 = 0.f;
#pragma unroll
    for (int k = 0; k < NQ; ++k) { wx1[k] = Wx[k * NP + j1]; wh1[k] = Wh[k * NP + j1]; }
    if (has2) {
        b2 = bias[j2];
#pragma unroll
        for (int k = 0; k < NQ; ++k) { wx2[k] = Wx[k * NP + j2]; wh2[k] = Wh[k * NP + j2]; }
    } else {
#pragma unroll
        for (int k = 0; k < NQ; ++k) { wx2[k] = 0.f; wh2[k] = 0.f; }
    }

    // ---- precompute px[t][j] = b + x_t@Wx (h-independent part of the recurrence)
    __builtin_amdgcn_wave_barrier();
#pragma unroll
    for (int t = 0; t < TT; ++t) {
        float a1 = b1, a2 = b2;
#pragma unroll
        for (int k = 0; k < NQ; ++k) {
            float xv = lds[XOFF + t * 10 + k];   // broadcast read
            a1 = fmaf(xv, wx1[k], a1);
            a2 = fmaf(xv, wx2[k], a2);
        }
        lds[PXO + t * NP + j1] = a1;
        if (has2) lds[PXO + t * NP + j2] = a2;
    }

    // ---- A1 setup: the 64 sincos angles, exactly one per lane.
    //  lanes 0-9:   forget  p[q]          lanes 10-29: input  p[10..29]
    //  lanes 30-49: cand    p[41+3q],p[42+3q]
    //  lanes 50-59: memory  p[70..79]     lanes 60-63: temporal m*0.05*p[80], m=1..4
    int aidx; float amul = 1.f;
    if (ln < 30) aidx = ln;
    else if (ln < 50) { int u = ln - 30; aidx = 41 + 3 * (u >> 1) + (u & 1); }
    else if (ln < 60) aidx = ln + 20;
    else { aidx = 80; amul = 0.05f * (float)(ln - 59); }

    // ---- A2/B role: (circuit c5, qubit q5) == (gate, k). c5: 0=f 1=i 2=cand 3=mq 4=tm
    const int c5 = ln / 10, q5 = ln - 10 * c5;
    // candidate CZ-graph neighbor masks
    const unsigned cm = (q5 == 0) ? 0x304u : (q5 == 1) ? 0x048u : (q5 == 2) ? 0x2F9u :
                        (q5 == 3) ? 0x086u : (q5 == 4) ? 0x044u : (q5 == 5) ? 0x204u :
                        (q5 == 6) ? 0x016u : (q5 == 7) ? 0x00Cu : (q5 == 8) ? 0x001u : 0x025u;
    // uniform product pass: input prefix prod(S), candidate graph prod(C)
    unsigned pmsk = 0u; int pbase = SOFF + 10;
    if (c5 == 1) pmsk = (1u << q5) - 1u;
    else if (c5 == 2) { pmsk = cm; pbase = COFF + 30; }
    // per-role gather indices into S/C arrays
    int a0 = 60, a2i = 62, a4 = 61, a5 = 63;
    if (c5 == 0)      { a0 = q5;          a2i = q5 ^ 1; }
    else if (c5 == 1) { a0 = 10 + 2 * q5; a2i = 11 + 2 * q5;
                        a4 = (q5 < 9) ? (12 + 2 * q5) : 61;
                        a5 = (q5 < 9) ? (13 + 2 * q5) : 63; }
    else if (c5 == 2) { a0 = 30 + 2 * q5; a2i = 31 + 2 * q5; }
    else if (c5 == 3) { a0 = 50 + q5;     a2i = 50 + (q5 ^ 1); }

    // ---- B weights: gate c5 -> R rows {0,1,3,4,5}; rr[30..31]=0 pads to 8x float4
    float rr[32];
    if (ln < 50) {
        const int gR = c5 + (c5 >= 2 ? 1 : 0);
#pragma unroll
        for (int f = 0; f < 30; ++f) rr[f] = R[gR * 300 + f * 10 + q5];
    } else {
#pragma unroll
        for (int f = 0; f < 30; ++f) rr[f] = 0.f;
    }
    rr[30] = 0.f; rr[31] = 0.f;

    // ---- constant o gate (circ_output feats = (0,1,0)^10)
    float o_val = 0.f;
    if (ln < 10) {
        float s = 0.f;
#pragma unroll
        for (int q = 0; q < NQ; ++q) s += R[600 + (3 * q + 1) * 10 + ln];
        o_val = sigm(s);
    }

    // ---- zero ft pad words (30..35 of each circuit row) + h init
    if (ln < 30) lds[FTO + (ln / 6) * 36 + 30 + (ln % 6)] = 0.f;
    if (ln < 12) lds[HOFF + ln] = 0.f;
    float creg = 0.f;
    __builtin_amdgcn_wave_barrier();

    const float r2c = 0.70710678118654752f;
    float* outg = out + (size_t)g * 80;

#pragma unroll 1
    for (int t = 0; t < TT; ++t) {
        // ===== P1: p = px + h@Wh (10-FMA chain, broadcast h reads) =====
        float p1v = lds[PXO + t * NP + j1];
        float p2v = has2 ? lds[PXO + t * NP + j2] : 0.f;
#pragma unroll
        for (int k = 0; k < NQ; ++k) {
            float hv = lds[HOFF + k];
            p1v = fmaf(hv, wh1[k], p1v);
            p2v = fmaf(hv, wh2[k], p2v);
        }
        __builtin_amdgcn_wave_barrier();

        // ===== A1: gather angle from p regs via shuffle, sincos, -> LDS =====
        float va = __shfl(p1v, aidx & 63, 64);
        float vb = __shfl(p2v, (aidx - 64) & 63, 64);
        float ang = ((aidx < 64) ? va : vb) * amul;
        float sv, cv;
        __sincosf(ang, &sv, &cv);
        lds[SOFF + ln] = sv;
        lds[COFF + ln] = cv;
        __builtin_amdgcn_wave_barrier();

        // ===== A2: 50 lanes produce 3 features each =====
        if (ln < 50) {
            // uniform masked product pass (broadcast reads, conflict-free)
            float prod = 1.f;
#pragma unroll
            for (int i = 0; i < 10; ++i) {
                float v = lds[pbase + 2 * i];
                prod *= ((pmsk >> i) & 1u) ? v : 1.f;
            }
            float v0 = lds[SOFF + a0],  w0 = lds[COFF + a0];
            float v2 = lds[SOFF + a2i], w2 = lds[COFF + a2i];
            float w4 = lds[COFF + a4],  w5 = lds[COFF + a5];
            float v6 = lds[SOFF + 63];
            float f0, f1, f2;
            if (c5 == 0) {                       // forget: RY, CZ pairs, T
                f0 = -v0; f1 = -r2c * w0 * v2; f2 = f1;
            } else if (c5 == 1) {                // input: RY,RZ + CNOT chain
                float Z = (q5 & 1) ? -prod : prod;      // prod_{i<q}(-sa_i)
                float xn = (q5 < 9) ? w4 * w5 : 1.f;
                f0 = -Z * v0;
                f1 = (w0 * w2) * xn;
                f2 = (w0 * v2) * (Z * xn);
            } else if (c5 == 2) {                // candidate: H, RZ RY RZ, CZ graph
                float m = v0 * prod;
                f0 = w0; f1 = m * w2; f2 = m * v2;
            } else if (c5 == 3) {                // memory: RY, CZ pairs
                f0 = -v0; f1 = -w0 * v2; f2 = 0.f;
            } else {                             // temporal (closed form)
                float s2 = v0, c2 = w0, s6 = v2, c6 = w2, c4v = w4, c8 = w5, s8 = v6;
                float z0 = c2, zs = 0.5f * (c2 - c6);
                float mre = 0.5f * c4v, mim = 0.25f * (s2 + s6);
                float E0im = z0 * s8, Esim = zs * s8;
                float cr0re = 0.5f * s2 * Esim, cr0im = -0.5f * s2 * c8;
                float EEre = c8 * c8 - Esim * Esim, EEim = 2.f * c8 * Esim;
                float EOre = c8 * c8 - E0im * Esim, EOim = c8 * Esim + E0im * c8;
                float cr1re = mre * EOre - mim * EOim, cr1im = mre * EOim + mim * EOre;
                float crmre = mre * EEre - mim * EEim, crmim = mre * EEim + mim * EEre;
                float cr9re = mre * c8 - mim * Esim,  cr9im = mre * Esim + mim * c8;
                f0 = (q5 == 0) ? z0 : zs;
                float re = (q5 == 0) ? cr0re : (q5 == 1) ? cr1re : (q5 == 9) ? cr9re : crmre;
                float im = (q5 == 0) ? cr0im : (q5 == 1) ? cr1im : (q5 == 9) ? cr9im : crmim;
                f1 = 2.f * re; f2 = 2.f * im;
            }
            const int fb = FTO + c5 * 36 + 3 * q5;
            lds[fb] = f0; lds[fb + 1] = f1; lds[fb + 2] = f2;
        }
        __builtin_amdgcn_wave_barrier();

        // ===== B: 50 dot-30 via 8x ds_read_b128 broadcast (stride 36: no conflicts) =====
        if (ln < 50) {
            const float4* fp = (const float4*)&lds[FTO + c5 * 36];
            float acc0 = 0.f, acc1 = 0.f;
#pragma unroll
            for (int f4 = 0; f4 < 8; f4 += 2) {
                float4 u = fp[f4], w = fp[f4 + 1];
                acc0 = fmaf(u.x, rr[4 * f4 + 0], acc0);
                acc0 = fmaf(u.y, rr[4 * f4 + 1], acc0);
                acc0 = fmaf(u.z, rr[4 * f4 + 2], acc0);
                acc0 = fmaf(u.w, rr[4 * f4 + 3], acc0);
                acc1 = fmaf(w.x, rr[4 * f4 + 4], acc1);
                acc1 = fmaf(w.y, rr[4 * f4 + 5], acc1);
                acc1 = fmaf(w.z, rr[4 * f4 + 6], acc1);
                acc1 = fmaf(w.w, rr[4 * f4 + 7], acc1);
            }
            lds[GOFF + ln] = acc0 + acc1;
        }
        __builtin_amdgcn_wave_barrier();

        // ===== C: cell update (10 lanes; c stays in registers) =====
        if (ln < 10) {
            float fz = sigm(lds[GOFF + ln]);
            float iz = sigm(lds[GOFF + 10 + ln]);
            float gz = tanh_(lds[GOFF + 20 + ln]);
            float mz = sigm(lds[GOFF + 30 + ln]);
            float tz = tanh_(lds[GOFF + 40 + ln]);
            creg = (fz * creg + iz * gz) * mz;
            float hn = o_val * tanh_(creg) + 0.1f * tz;
            lds[HOFF + ln] = hn;
            outg[t * 10 + ln] = hn;   // async store, never drained by a barrier
        }
        __builtin_amdgcn_wave_barrier();
    }
}

extern "C" void kernel_launch(void* const* d_in, const int* in_sizes, int n_in,
                              void* d_out, int out_size, void* d_ws, size_t ws_size,
                              hipStream_t stream) {
    const float* x = (const float*)d_in[0];     // (2048, 8, 10) f32
    const float* Wx = (const float*)d_in[1];    // (10, 81)
    const float* Wh = (const float*)d_in[2];    // (10, 81)
    const float* bias = (const float*)d_in[3];  // (81,)
    const float* R = (const float*)d_in[4];     // (6, 30, 10)
    float* out = (float*)d_out;                 // (2048, 8, 10) f32

    // one wave per batch element: 2048 waves = 512 blocks x 4 waves
    qlstm_kernel<<<dim3(512), dim3(256), 0, stream>>>(x, Wx, Wh, bias, R, out);
}